// Round 4
// baseline (555.487 us; speedup 1.0000x reference)
//
#include <hip/hip_runtime.h>
#include <hip/hip_bf16.h>
#include <cstdint>
#include <cstddef>

// Problem constants
#define Bsz 8192
#define Hdim 2048
#define Kdim 4096   // EFF
#define Nall 4096   // 2*H in Wt: rows 0..2047 cand, 2048..4095 gate

// GEMM tiling: 8-phase 256^2 template adapted to dual-output.
#define BM 256
#define BNH 128
#define BK 64
#define NTILES (Kdim / BK)   // 64
#define NITER (NTILES / 2)   // 32

typedef __attribute__((ext_vector_type(8))) short short8;   // 8 bf16
typedef __attribute__((ext_vector_type(4))) short short4v;  // 4 bf16 (8B)
typedef __attribute__((ext_vector_type(4))) float floatx4;

__device__ __forceinline__ short f2bf(float f) {
    unsigned u = __float_as_uint(f);
    unsigned r = (u + 0x7fffu + ((u >> 16) & 1u)) >> 16;
    return (short)(r & 0xffffu);
}
__device__ __forceinline__ float fast_tanh(float x) {
    float e = __expf(2.f * x);
    return 1.f - 2.f / (e + 1.f);
}
__device__ __forceinline__ float fast_sigmoid(float x) {
    return 1.f / (1.f + __expf(-x));
}
__device__ __forceinline__ void g2l16(const void* g, void* l) {
    __builtin_amdgcn_global_load_lds(
        (const __attribute__((address_space(1))) unsigned int*)g,
        (__attribute__((address_space(3))) unsigned int*)l,
        16, 0, 0);
}

// Device-scope grid barrier: release fence -> count -> spin -> acquire fence.
// __threadfence on gfx950 = agent-scope fence (buffer_wbl2/buffer_inv), so
// cross-XCD L2 non-coherence is handled. Watchdog: fail loud, never hang.
__device__ __forceinline__ void grid_sync(int* cnt, int target) {
    __syncthreads();                 // drains vmcnt: all block stores issued
    if (threadIdx.x == 0) {
        __threadfence();             // release: flush L2 to coherence point
        atomicAdd(cnt, 1);
        int guard = 0;
        while (atomicAdd(cnt, 0) < target && guard < (1 << 17)) {
            __builtin_amdgcn_s_sleep(2);
            ++guard;
        }
        __threadfence();             // acquire: invalidate stale L2 lines
    }
    __syncthreads();
}

// ---- gemm helpers (unchanged) ----
__device__ __forceinline__ void rdA4(const short* base, const int i0,
                                     short8 (&aF)[4][2],
                                     const int cs0, const int cs1) {
#pragma unroll
    for (int i = 0; i < 4; ++i) {
        aF[i][0] = *(const short8*)(base + (i0 + i) * 16 * BK + cs0);
        aF[i][1] = *(const short8*)(base + (i0 + i) * 16 * BK + cs1);
    }
}
__device__ __forceinline__ void rdB2(const short* base, const int j0,
                                     short8 (&bF)[2][2],
                                     const int cs0, const int cs1) {
#pragma unroll
    for (int j = 0; j < 2; ++j) {
        bF[j][0] = *(const short8*)(base + (j0 + j) * 16 * BK + cs0);
        bF[j][1] = *(const short8*)(base + (j0 + j) * 16 * BK + cs1);
    }
}
__device__ __forceinline__ void mma16(floatx4 (&acc)[8][4], const int ia,
                                      const int jb, const short8 (&aF)[4][2],
                                      const short8 (&bF)[2][2]) {
#pragma unroll
    for (int i = 0; i < 4; ++i)
#pragma unroll
        for (int j = 0; j < 2; ++j) {
            acc[ia + i][jb + j] = __builtin_amdgcn_mfma_f32_16x16x32_bf16(
                aF[i][0], bF[j][0], acc[ia + i][jb + j], 0, 0, 0);
            acc[ia + i][jb + j] = __builtin_amdgcn_mfma_f32_16x16x32_bf16(
                aF[i][1], bF[j][1], acc[ia + i][jb + j], 0, 0, 0);
        }
}

#define STAGE(srcArr, h, dstBase, dstOff, koff) do {               \
    g2l16(srcArr[h][0] + (koff), (dstBase) + dstOff[h][0]);        \
    g2l16(srcArr[h][1] + (koff), (dstBase) + dstOff[h][1]); } while (0)

#define BAR()   __builtin_amdgcn_s_barrier()
#define LGKM0() asm volatile("s_waitcnt lgkmcnt(0)" ::: "memory")
#define VM6()   asm volatile("s_waitcnt vmcnt(6)" ::: "memory")
#define VM0()   asm volatile("s_waitcnt vmcnt(0)" ::: "memory")
#define PRIO1() __builtin_amdgcn_s_setprio(1)
#define PRIO0() __builtin_amdgcn_s_setprio(0)

// ---------------------------------------------------------------------------
// MEGA kernel: one persistent dispatch, 256 blocks (1/CU), 3 phases.
//   A: build Wt + Acat    B: 8-phase gemm x2 tile-assignments    C: layernorm
// ---------------------------------------------------------------------------
__global__ __launch_bounds__(512, 2) void mega(
    const float* __restrict__ x, const float* __restrict__ st,
    const float* __restrict__ Wc, const float* __restrict__ Uc,
    const float* __restrict__ bc, const float* __restrict__ Wg,
    const float* __restrict__ Ug, const float* __restrict__ bg,
    const float* __restrict__ lstep, const float* __restrict__ gam,
    const float* __restrict__ bet,
    short* __restrict__ Wt, short* __restrict__ Acat,
    float* __restrict__ h, float* __restrict__ out,
    int* __restrict__ cnt)
{
    __shared__ __attribute__((aligned(16))) short lds[4][256 * BK]; // 128 KB
    const int tid = threadIdx.x;
    const int bid = blockIdx.x;            // 0..255
    const int lane = tid & 63;
    const int w = tid >> 6;                // 0..7

    // ================= Phase A: prep =================
    {
        // A1: build_wt — 4 tiles of 64n x 256k per block.
        float (*tile)[257] = (float(*)[257])(&lds[0][0]);   // 65.8 KB
        const int txl = tid & 15;          // float4 n-col group
        const int tyl = tid >> 4;          // 0..31 k-row
#pragma unroll 1
        for (int t4 = 0; t4 < 4; ++t4) {
            int t = bid * 4 + t4;          // 0..1023
            int nt = (t & 63) * 64;
            int kt = (t >> 6) * 256;
            const bool isGate = (nt >= Hdim);
            const float* W = isGate ? Wg : Wc;
            const float* U = isGate ? Ug : Uc;
            const int ncol = isGate ? (nt - Hdim) : nt;
            const bool useU = (kt >= Hdim);
#pragma unroll
            for (int r = 0; r < 256; r += 32) {
                int k = kt + tyl + r;
                float4 v = *(const float4*)(W + (size_t)k * Hdim + ncol + txl * 4);
                if (useU) {
                    float4 u = *(const float4*)(U + (size_t)(k - Hdim) * Hdim + ncol + txl * 4);
                    v.x += u.x; v.y += u.y; v.z += u.z; v.w += u.w;
                }
                int kl = tyl + r;
                tile[txl * 4 + 0][kl] = v.x;
                tile[txl * 4 + 1][kl] = v.y;
                tile[txl * 4 + 2][kl] = v.z;
                tile[txl * 4 + 3][kl] = v.w;
            }
            __syncthreads();
            // write: n = tid&63 (2-way LDS reads, conflict-free), 64B/thread
            const int n  = tid & 63;
            const int kq = (tid >> 6) * 32;
            short* dst = Wt + (size_t)(nt + n) * Kdim + kt + kq;
#pragma unroll
            for (int i = 0; i < 4; ++i) {
                short8 o;
#pragma unroll
                for (int e = 0; e < 8; ++e) o[e] = f2bf(tile[n][kq + i * 8 + e]);
                *(short8*)(dst + i * 8) = o;
            }
            __syncthreads();
        }
        // A2: build_acat — 32 wave-segments of 512 elems per wave.
#pragma unroll 1
        for (int i = 0; i < 32; ++i) {
            int seg = bid * 8 + w + i * 2048;          // 0..65535
            size_t base = (size_t)seg * 512;
            int row = (int)(base >> 12);
            int c = (int)(base & 4095);
            const float* src = (c < Hdim) ? (x + (size_t)row * Hdim + c)
                                          : (st + (size_t)row * Hdim + (c - Hdim));
            float4 v0 = *(const float4*)(src + lane * 4);
            float4 v1 = *(const float4*)(src + 256 + lane * 4);
            short4v o0, o1;
            o0[0] = f2bf(v0.x); o0[1] = f2bf(v0.y); o0[2] = f2bf(v0.z); o0[3] = f2bf(v0.w);
            o1[0] = f2bf(v1.x); o1[1] = f2bf(v1.y); o1[2] = f2bf(v1.z); o1[3] = f2bf(v1.w);
            short* d = Acat + base;
            *(short4v*)(d + lane * 4) = o0;
            *(short4v*)(d + 256 + lane * 4) = o1;
        }
    }
    grid_sync(cnt, 256);

    // ================= Phase B: gemm (x2 assignments) =================
    {
        short* const sA0 = &lds[0][0];
        short* const sA1 = &lds[1][0];
        short* const sB0 = &lds[2][0];
        short* const sB1 = &lds[3][0];
        const int wm = w >> 2;
        const int wn = w & 3;
        const int r8 = lane >> 3;
        const int c8 = ((lane & 7) ^ r8) * 8;
        const int fr = lane & 15;
        const int j4 = lane >> 4;
        const int cs0 = ((j4 ^ (fr & 7)) * 8);
        const int cs1 = (((4 + j4) ^ (fr & 7)) * 8);
        const short* A0f = sA0 + (wm * 128 + fr) * BK;
        const short* A1f = sA1 + (wm * 128 + fr) * BK;
        const short* B0f = sB0 + (wn * 64 + fr) * BK;
        const short* B1f = sB1 + (wn * 64 + fr) * BK;

#pragma unroll 1
        for (int rep = 0; rep < 2; ++rep) {
            const int vb = bid + rep * 256;              // virtual block 0..511
            const int swz = (vb & 7) * 64 + (vb >> 3);   // XCD-bijective
            const int m0 = (swz >> 4) * BM;
            const int n0 = (swz & 15) * BNH;

            const short* aSrc[2][2];
            const short* bSrc[2][2];
            int dstA[2][2], dstB[2][2];
#pragma unroll
            for (int hh = 0; hh < 2; ++hh)
#pragma unroll
                for (int q = 0; q < 2; ++q) {
                    int f = w * 2 + q;
                    int ra = f * 8 + hh * 64 + (f & 8) * 8;
                    int rb = (f >> 2) * 64 + (f & 3) * 8 + hh * 32;
                    aSrc[hh][q] = Acat + (size_t)(m0 + ra + r8) * Kdim + c8;
                    int lr = rb + r8;
                    int btrow = n0 + ((lr >> 6) << 5) + (lr & 31)
                                + ((lr & 32) ? Hdim : 0);
                    bSrc[hh][q] = Wt + (size_t)btrow * Kdim + c8;
                    dstA[hh][q] = ra * BK;
                    dstB[hh][q] = rb * BK;
                }

            floatx4 acc[8][4];
#pragma unroll
            for (int i = 0; i < 8; ++i)
#pragma unroll
                for (int j = 0; j < 4; ++j) {
                    floatx4 z = {0.f, 0.f, 0.f, 0.f};
                    acc[i][j] = z;
                }
            short8 aF[4][2], bLo[2][2], bHi[2][2];

            // prologue: t0 fully, t1 minus A-h1
            STAGE(aSrc, 0, sA0, dstA, 0);
            STAGE(aSrc, 1, sA0, dstA, 0);
            STAGE(bSrc, 0, sB0, dstB, 0);
            STAGE(bSrc, 1, sB0, dstB, 0);
            STAGE(aSrc, 0, sA1, dstA, BK);
            STAGE(bSrc, 0, sB1, dstB, BK);
            STAGE(bSrc, 1, sB1, dstB, BK);
            VM6();
            BAR();

#pragma unroll 1
            for (int it = 0; it < NITER; ++it) {
                const bool nl = (it < NITER - 1);
                const int k1  = (2 * it + 1) * BK;
                const int k02 = (2 * it + 2) * BK;
                const int k12 = (2 * it + 3) * BK;

                // P1
                rdA4(A0f, 0, aF, cs0, cs1);
                rdB2(B0f, 0, bLo, cs0, cs1);
                STAGE(aSrc, 1, sA1, dstA, k1);
                BAR(); LGKM0(); PRIO1();
                mma16(acc, 0, 0, aF, bLo);
                PRIO0(); BAR();
                // P2
                rdB2(B0f, 2, bHi, cs0, cs1);
                if (nl) { STAGE(aSrc, 0, sA0, dstA, k02); }
                BAR(); LGKM0(); PRIO1();
                mma16(acc, 0, 2, aF, bHi);
                PRIO0(); BAR();
                // P3
                rdA4(A0f, 4, aF, cs0, cs1);
                if (nl) { STAGE(bSrc, 0, sB0, dstB, k02); }
                BAR(); LGKM0(); PRIO1();
                mma16(acc, 4, 0, aF, bLo);
                PRIO0(); BAR();
                // P4
                if (nl) { STAGE(bSrc, 1, sB0, dstB, k02); VM6(); }
                else    { VM0(); }
                BAR(); PRIO1();
                mma16(acc, 4, 2, aF, bHi);
                PRIO0(); BAR();
                // P5
                rdA4(A1f, 0, aF, cs0, cs1);
                rdB2(B1f, 0, bLo, cs0, cs1);
                if (nl) { STAGE(aSrc, 1, sA0, dstA, k02); }
                BAR(); LGKM0(); PRIO1();
                mma16(acc, 0, 0, aF, bLo);
                PRIO0(); BAR();
                // P6
                rdB2(B1f, 2, bHi, cs0, cs1);
                if (nl) { STAGE(aSrc, 0, sA1, dstA, k12); }
                BAR(); LGKM0(); PRIO1();
                mma16(acc, 0, 2, aF, bHi);
                PRIO0(); BAR();
                // P7
                rdA4(A1f, 4, aF, cs0, cs1);
                if (nl) { STAGE(bSrc, 0, sB1, dstB, k12); }
                BAR(); LGKM0(); PRIO1();
                mma16(acc, 4, 0, aF, bLo);
                PRIO0(); BAR();
                // P8
                if (nl) { STAGE(bSrc, 1, sB1, dstB, k12); VM6(); }
                BAR(); PRIO1();
                mma16(acc, 4, 2, aF, bHi);
                PRIO0(); BAR();
            }

            // epilogue
            const int cn = lane & 15;
            const int cr = j4 * 4;
            float bcv[2], bgv[2], alv[2];
#pragma unroll
            for (int j = 0; j < 2; ++j) {
                int col = n0 + wn * 32 + j * 16 + cn;
                bcv[j] = bc[col];
                bgv[j] = bg[col];
                alv[j] = __expf(-__expf(-lstep[col]));
            }
#pragma unroll
            for (int i = 0; i < 8; ++i) {
                int rowb = m0 + wm * 128 + i * 16 + cr;
#pragma unroll
                for (int r = 0; r < 4; ++r) {
                    int row = rowb + r;
                    const float* sp = st + (size_t)row * Hdim;
                    float* hp = h + (size_t)row * Hdim;
#pragma unroll
                    for (int j = 0; j < 2; ++j) {
                        int col = n0 + wn * 32 + j * 16 + cn;
                        float cand = fast_tanh(acc[i][j][r] + bcv[j]);
                        float gate = fast_sigmoid(acc[i][j + 2][r] + bgv[j]);
                        float al = alv[j];
                        hp[col] = al * sp[col] + (1.f - al) * gate * cand;
                    }
                }
            }
        }
    }
    grid_sync(cnt, 512);

    // ================= Phase C: layernorm =================
#pragma unroll 1
    for (int i = 0; i < 4; ++i) {
        int b = bid * 32 + w * 4 + i;      // 256*32 = 8192 rows
        const float* hp = h + (size_t)b * Hdim;
        float4 v[8];
        float sum = 0.f, ss = 0.f;
#pragma unroll
        for (int q = 0; q < 8; ++q) {
            v[q] = *(const float4*)(hp + q * 256 + lane * 4);
            sum += v[q].x + v[q].y + v[q].z + v[q].w;
            ss  += v[q].x * v[q].x + v[q].y * v[q].y
                 + v[q].z * v[q].z + v[q].w * v[q].w;
        }
#pragma unroll
        for (int off = 1; off < 64; off <<= 1) {
            sum += __shfl_xor(sum, off);
            ss  += __shfl_xor(ss, off);
        }
        const float inv = 1.f / (float)Hdim;
        float mu = sum * inv;
        float var = ss * inv - mu * mu;
        float rs = rsqrtf(var + 1e-5f);
        float* op = out + (size_t)b * Hdim;
#pragma unroll
        for (int q = 0; q < 8; ++q) {
            float4 g  = *(const float4*)(gam + q * 256 + lane * 4);
            float4 be = *(const float4*)(bet + q * 256 + lane * 4);
            float4 o;
            o.x = (v[q].x - mu) * rs * g.x + be.x;
            o.y = (v[q].y - mu) * rs * g.y + be.y;
            o.z = (v[q].z - mu) * rs * g.z + be.z;
            o.w = (v[q].w - mu) * rs * g.w + be.w;
            *(float4*)(op + q * 256 + lane * 4) = o;
        }
    }
}

// ===========================================================================
// Fallback path (exact R3 kernels), used only if ws_size lacks room for cnt.
// ===========================================================================
__global__ __launch_bounds__(256) void build_wt(
    const float* __restrict__ Wc, const float* __restrict__ Uc,
    const float* __restrict__ Wg, const float* __restrict__ Ug,
    short* __restrict__ Wt)
{
    __shared__ float tile[64][257];
    const int nt = blockIdx.x * 64;
    const int kt = blockIdx.y * 256;
    const int tx = threadIdx.x & 15;
    const int ty = threadIdx.x >> 4;
    const bool isGate = (nt >= Hdim);
    const float* W = isGate ? Wg : Wc;
    const float* U = isGate ? Ug : Uc;
    const int ncol = isGate ? (nt - Hdim) : nt;
    const bool useU = (kt >= Hdim);
#pragma unroll 4
    for (int r = 0; r < 256; r += 16) {
        int k = kt + ty + r;
        float4 v = *(const float4*)(W + (size_t)k * Hdim + ncol + tx * 4);
        if (useU) {
            float4 u = *(const float4*)(U + (size_t)(k - Hdim) * Hdim + ncol + tx * 4);
            v.x += u.x; v.y += u.y; v.z += u.z; v.w += u.w;
        }
        int kl = ty + r;
        tile[tx * 4 + 0][kl] = v.x;
        tile[tx * 4 + 1][kl] = v.y;
        tile[tx * 4 + 2][kl] = v.z;
        tile[tx * 4 + 3][kl] = v.w;
    }
    __syncthreads();
    const int n  = threadIdx.x >> 2;
    const int kq = (threadIdx.x & 3) * 64;
    short* dst = Wt + (size_t)(nt + n) * Kdim + kt + kq;
#pragma unroll
    for (int i = 0; i < 8; ++i) {
        short8 o;
#pragma unroll
        for (int e = 0; e < 8; ++e) o[e] = f2bf(tile[n][kq + i * 8 + e]);
        *(short8*)(dst + i * 8) = o;
    }
}

__global__ __launch_bounds__(256) void build_acat(
    const float* __restrict__ x, const float* __restrict__ st,
    short* __restrict__ A)
{
    const int lane = threadIdx.x & 63;
    const int wid = (blockIdx.x * 256 + threadIdx.x) >> 6;
    const size_t base = (size_t)wid * 512;
    const int row = (int)(base >> 12);
    const int c = (int)(base & 4095);
    const float* src = (c < Hdim) ? (x + (size_t)row * Hdim + c)
                                  : (st + (size_t)row * Hdim + (c - Hdim));
    float4 v0 = *(const float4*)(src + lane * 4);
    float4 v1 = *(const float4*)(src + 256 + lane * 4);
    short4v o0, o1;
    o0[0] = f2bf(v0.x); o0[1] = f2bf(v0.y); o0[2] = f2bf(v0.z); o0[3] = f2bf(v0.w);
    o1[0] = f2bf(v1.x); o1[1] = f2bf(v1.y); o1[2] = f2bf(v1.z); o1[3] = f2bf(v1.w);
    short* d = A + base;
    *(short4v*)(d + lane * 4) = o0;
    *(short4v*)(d + 256 + lane * 4) = o1;
}

__global__ __launch_bounds__(512, 2) void gemm_fused(
    const short* __restrict__ A, const short* __restrict__ Bt,
    const float* __restrict__ st, const float* __restrict__ bc,
    const float* __restrict__ bg, const float* __restrict__ lstep,
    float* __restrict__ Hout)
{
    __shared__ __attribute__((aligned(16))) short lds[4][256 * BK];
    short* const sA0 = &lds[0][0];
    short* const sA1 = &lds[1][0];
    short* const sB0 = &lds[2][0];
    short* const sB1 = &lds[3][0];
    const int tid = threadIdx.x;
    const int lane = tid & 63;
    const int w = tid >> 6;
    const int wm = w >> 2;
    const int wn = w & 3;
    const int bid = blockIdx.x;
    const int swz = (bid & 7) * 64 + (bid >> 3);
    const int m0 = (swz >> 4) * BM;
    const int n0 = (swz & 15) * BNH;
    const int r8 = lane >> 3;
    const int c8 = ((lane & 7) ^ r8) * 8;
    const short* aSrc[2][2];
    const short* bSrc[2][2];
    int dstA[2][2], dstB[2][2];
#pragma unroll
    for (int hh = 0; hh < 2; ++hh)
#pragma unroll
        for (int q = 0; q < 2; ++q) {
            int f = w * 2 + q;
            int ra = f * 8 + hh * 64 + (f & 8) * 8;
            int rb = (f >> 2) * 64 + (f & 3) * 8 + hh * 32;
            aSrc[hh][q] = A + (size_t)(m0 + ra + r8) * Kdim + c8;
            int lr = rb + r8;
            int btrow = n0 + ((lr >> 6) << 5) + (lr & 31) + ((lr & 32) ? Hdim : 0);
            bSrc[hh][q] = Bt + (size_t)btrow * Kdim + c8;
            dstA[hh][q] = ra * BK;
            dstB[hh][q] = rb * BK;
        }
    const int fr = lane & 15;
    const int j4 = lane >> 4;
    const int cs0 = ((j4 ^ (fr & 7)) * 8);
    const int cs1 = (((4 + j4) ^ (fr & 7)) * 8);
    const short* A0f = sA0 + (wm * 128 + fr) * BK;
    const short* A1f = sA1 + (wm * 128 + fr) * BK;
    const short* B0f = sB0 + (wn * 64 + fr) * BK;
    const short* B1f = sB1 + (wn * 64 + fr) * BK;
    floatx4 acc[8][4];
#pragma unroll
    for (int i = 0; i < 8; ++i)
#pragma unroll
        for (int j = 0; j < 4; ++j) {
            floatx4 z = {0.f, 0.f, 0.f, 0.f};
            acc[i][j] = z;
        }
    short8 aF[4][2], bLo[2][2], bHi[2][2];
    STAGE(aSrc, 0, sA0, dstA, 0);
    STAGE(aSrc, 1, sA0, dstA, 0);
    STAGE(bSrc, 0, sB0, dstB, 0);
    STAGE(bSrc, 1, sB0, dstB, 0);
    STAGE(aSrc, 0, sA1, dstA, BK);
    STAGE(bSrc, 0, sB1, dstB, BK);
    STAGE(bSrc, 1, sB1, dstB, BK);
    VM6();
    BAR();
    for (int it = 0; it < NITER; ++it) {
        const bool nl = (it < NITER - 1);
        const int k1  = (2 * it + 1) * BK;
        const int k02 = (2 * it + 2) * BK;
        const int k12 = (2 * it + 3) * BK;
        rdA4(A0f, 0, aF, cs0, cs1);
        rdB2(B0f, 0, bLo, cs0, cs1);
        STAGE(aSrc, 1, sA1, dstA, k1);
        BAR(); LGKM0(); PRIO1();
        mma16(acc, 0, 0, aF, bLo);
        PRIO0(); BAR();
        rdB2(B0f, 2, bHi, cs0, cs1);
        if (nl) { STAGE(aSrc, 0, sA0, dstA, k02); }
        BAR(); LGKM0(); PRIO1();
        mma16(acc, 0, 2, aF, bHi);
        PRIO0(); BAR();
        rdA4(A0f, 4, aF, cs0, cs1);
        if (nl) { STAGE(bSrc, 0, sB0, dstB, k02); }
        BAR(); LGKM0(); PRIO1();
        mma16(acc, 4, 0, aF, bLo);
        PRIO0(); BAR();
        if (nl) { STAGE(bSrc, 1, sB0, dstB, k02); VM6(); }
        else    { VM0(); }
        BAR(); PRIO1();
        mma16(acc, 4, 2, aF, bHi);
        PRIO0(); BAR();
        rdA4(A1f, 0, aF, cs0, cs1);
        rdB2(B1f, 0, bLo, cs0, cs1);
        if (nl) { STAGE(aSrc, 1, sA0, dstA, k02); }
        BAR(); LGKM0(); PRIO1();
        mma16(acc, 0, 0, aF, bLo);
        PRIO0(); BAR();
        rdB2(B1f, 2, bHi, cs0, cs1);
        if (nl) { STAGE(aSrc, 0, sA1, dstA, k12); }
        BAR(); LGKM0(); PRIO1();
        mma16(acc, 0, 2, aF, bHi);
        PRIO0(); BAR();
        rdA4(A1f, 4, aF, cs0, cs1);
        if (nl) { STAGE(bSrc, 0, sB1, dstB, k12); }
        BAR(); LGKM0(); PRIO1();
        mma16(acc, 4, 0, aF, bLo);
        PRIO0(); BAR();
        if (nl) { STAGE(bSrc, 1, sB1, dstB, k12); VM6(); }
        BAR(); PRIO1();
        mma16(acc, 4, 2, aF, bHi);
        PRIO0(); BAR();
    }
    const int cn = lane & 15;
    const int cr = j4 * 4;
    float bcv[2], bgv[2], alv[2];
#pragma unroll
    for (int j = 0; j < 2; ++j) {
        int col = n0 + wn * 32 + j * 16 + cn;
        bcv[j] = bc[col];
        bgv[j] = bg[col];
        alv[j] = __expf(-__expf(-lstep[col]));
    }
#pragma unroll
    for (int i = 0; i < 8; ++i) {
        int rowb = m0 + wm * 128 + i * 16 + cr;
#pragma unroll
        for (int r = 0; r < 4; ++r) {
            int row = rowb + r;
            const float* sp = st + (size_t)row * Hdim;
            float* hp = Hout + (size_t)row * Hdim;
#pragma unroll
            for (int j = 0; j < 2; ++j) {
                int col = n0 + wn * 32 + j * 16 + cn;
                float cand = fast_tanh(acc[i][j][r] + bcv[j]);
                float gate = fast_sigmoid(acc[i][j + 2][r] + bgv[j]);
                float al = alv[j];
                hp[col] = al * sp[col] + (1.f - al) * gate * cand;
            }
        }
    }
}

__global__ __launch_bounds__(256) void ln_k(
    const float* __restrict__ h, const float* __restrict__ gam,
    const float* __restrict__ bet, float* __restrict__ out)
{
    const int lane = threadIdx.x & 63;
    const int b = blockIdx.x * 4 + (threadIdx.x >> 6);
    const float* hp = h + (size_t)b * Hdim;
    float4 v[8];
    float sum = 0.f, ss = 0.f;
#pragma unroll
    for (int i = 0; i < 8; ++i) {
        v[i] = *(const float4*)(hp + i * 256 + lane * 4);
        sum += v[i].x + v[i].y + v[i].z + v[i].w;
        ss  += v[i].x * v[i].x + v[i].y * v[i].y
             + v[i].z * v[i].z + v[i].w * v[i].w;
    }
#pragma unroll
    for (int off = 1; off < 64; off <<= 1) {
        sum += __shfl_xor(sum, off);
        ss  += __shfl_xor(ss, off);
    }
    const float inv = 1.f / (float)Hdim;
    float mu = sum * inv;
    float var = ss * inv - mu * mu;
    float rs = rsqrtf(var + 1e-5f);
    float* op = out + (size_t)b * Hdim;
#pragma unroll
    for (int i = 0; i < 8; ++i) {
        float4 g  = *(const float4*)(gam + i * 256 + lane * 4);
        float4 be = *(const float4*)(bet + i * 256 + lane * 4);
        float4 o;
        o.x = (v[i].x - mu) * rs * g.x + be.x;
        o.y = (v[i].y - mu) * rs * g.y + be.y;
        o.z = (v[i].z - mu) * rs * g.z + be.z;
        o.w = (v[i].w - mu) * rs * g.w + be.w;
        *(float4*)(op + i * 256 + lane * 4) = o;
    }
}

// ---------------------------------------------------------------------------
extern "C" void kernel_launch(void* const* d_in, const int* in_sizes, int n_in,
                              void* d_out, int out_size, void* d_ws, size_t ws_size,
                              hipStream_t stream)
{
    const float* x_t   = (const float*)d_in[0];
    const float* state = (const float*)d_in[1];
    const float* Wc    = (const float*)d_in[2];
    const float* Uc    = (const float*)d_in[3];
    const float* bc    = (const float*)d_in[4];
    const float* Wg    = (const float*)d_in[5];
    const float* Ug    = (const float*)d_in[6];
    const float* bg    = (const float*)d_in[7];
    const float* lstep = (const float*)d_in[8];
    const float* gam   = (const float*)d_in[9];
    const float* bet   = (const float*)d_in[10];
    float* out = (float*)d_out;

    // workspace: Wt (32MB) | Acat (64MB) | h (64MB fp32) | cnt (64B)
    char* ws = (char*)d_ws;
    short* Wt   = (short*)ws;
    short* Acat = (short*)(ws + (size_t)32 * 1024 * 1024);
    float* h    = (float*)(ws + (size_t)96 * 1024 * 1024);
    int*   cnt  = (int*)(ws + (size_t)160 * 1024 * 1024);

    if (ws_size >= (size_t)160 * 1024 * 1024 + 64) {
        hipMemsetAsync(cnt, 0, 64, stream);
        mega<<<256, 512, 0, stream>>>(x_t, state, Wc, Uc, bc, Wg, Ug, bg,
                                      lstep, gam, bet, Wt, Acat, h, out, cnt);
    } else {
        build_wt<<<dim3(Nall / 64, Kdim / 256), 256, 0, stream>>>(Wc, Uc, Wg, Ug, Wt);
        build_acat<<<(Bsz * (Kdim / 8)) / 256, 256, 0, stream>>>(x_t, state, Acat);
        gemm_fused<<<dim3((Bsz / BM) * (Hdim / BNH)), 512, 0, stream>>>(
            Acat, Wt, state, bc, bg, lstep, h);
        ln_k<<<Bsz / 4, 256, 0, stream>>>(h, gam, bet, out);
    }
}

// Round 5
// 492.714 us; speedup vs baseline: 1.1274x; 1.1274x over previous
//
#include <hip/hip_runtime.h>
#include <hip/hip_bf16.h>
#include <cstdint>
#include <cstddef>

// Problem constants
#define Bsz 8192
#define Hdim 2048
#define Kdim 4096   // EFF
#define Nall 4096   // 2*H in Wt: rows 0..2047 cand, 2048..4095 gate

// GEMM tiling: 8-phase 256^2 template adapted to dual-output.
// Block tile: 256(m) x 128 h-cols, B-tile = 256 rows (cand|gate interleaved
// per-wave). BK=64, 8 waves (2M x 4N), 128 KiB LDS double-buffered.
#define BM 256
#define BNH 128
#define BK 64
#define NTILES (Kdim / BK)   // 64
#define NITER (NTILES / 2)   // 32

typedef __attribute__((ext_vector_type(8))) short short8;   // 8 bf16
typedef __attribute__((ext_vector_type(4))) short short4v;  // 4 bf16 (8B)
typedef __attribute__((ext_vector_type(4))) float floatx4;

// fp32 -> bf16 bits, round-to-nearest-even
__device__ __forceinline__ short f2bf(float f) {
    unsigned u = __float_as_uint(f);
    unsigned r = (u + 0x7fffu + ((u >> 16) & 1u)) >> 16;
    return (short)(r & 0xffffu);
}
__device__ __forceinline__ float bf2f(short s) {
    return __uint_as_float(((unsigned)(unsigned short)s) << 16);
}
__device__ __forceinline__ float fast_tanh(float x) {
    float e = __expf(2.f * x);
    return 1.f - 2.f / (e + 1.f);
}
__device__ __forceinline__ float fast_sigmoid(float x) {
    return 1.f / (1.f + __expf(-x));
}
__device__ __forceinline__ void g2l16(const void* g, void* l) {
    __builtin_amdgcn_global_load_lds(
        (const __attribute__((address_space(1))) unsigned int*)g,
        (__attribute__((address_space(3))) unsigned int*)l,
        16, 0, 0);
}

// ---------------------------------------------------------------------------
// Kernel 1: weight build + transpose, 256(k) x 64(n) tiles (R3 version —
// support kernels proven BW-floor-invariant across 4 rewrites; unchanged).
// ---------------------------------------------------------------------------
__global__ __launch_bounds__(256) void build_wt(
    const float* __restrict__ Wc, const float* __restrict__ Uc,
    const float* __restrict__ Wg, const float* __restrict__ Ug,
    short* __restrict__ Wt)
{
    __shared__ float tile[64][257];
    const int nt = blockIdx.x * 64;
    const int kt = blockIdx.y * 256;
    const int tx = threadIdx.x & 15;
    const int ty = threadIdx.x >> 4;
    const bool isGate = (nt >= Hdim);
    const float* W = isGate ? Wg : Wc;
    const float* U = isGate ? Ug : Uc;
    const int ncol = isGate ? (nt - Hdim) : nt;
    const bool useU = (kt >= Hdim);
#pragma unroll 4
    for (int r = 0; r < 256; r += 16) {
        int k = kt + ty + r;
        float4 v = *(const float4*)(W + (size_t)k * Hdim + ncol + tx * 4);
        if (useU) {
            float4 u = *(const float4*)(U + (size_t)(k - Hdim) * Hdim + ncol + tx * 4);
            v.x += u.x; v.y += u.y; v.z += u.z; v.w += u.w;
        }
        int kl = ty + r;
        tile[tx * 4 + 0][kl] = v.x;
        tile[tx * 4 + 1][kl] = v.y;
        tile[tx * 4 + 2][kl] = v.z;
        tile[tx * 4 + 3][kl] = v.w;
    }
    __syncthreads();
    const int n  = threadIdx.x >> 2;
    const int kq = (threadIdx.x & 3) * 64;
    short* dst = Wt + (size_t)(nt + n) * Kdim + kt + kq;
#pragma unroll
    for (int i = 0; i < 8; ++i) {
        short8 o;
#pragma unroll
        for (int e = 0; e < 8; ++e) o[e] = f2bf(tile[n][kq + i * 8 + e]);
        *(short8*)(dst + i * 8) = o;
    }
}

// ---------------------------------------------------------------------------
// Kernel 2: Acat[b][k] (bf16) = k<2048 ? x_t[b][k] : state[b][k-2048]
// (R3 version, unchanged)
// ---------------------------------------------------------------------------
__global__ __launch_bounds__(256) void build_acat(
    const float* __restrict__ x, const float* __restrict__ st,
    short* __restrict__ A)
{
    const int lane = threadIdx.x & 63;
    const int wid = (blockIdx.x * 256 + threadIdx.x) >> 6;
    const size_t base = (size_t)wid * 512;
    const int row = (int)(base >> 12);
    const int c = (int)(base & 4095);
    const float* src = (c < Hdim) ? (x + (size_t)row * Hdim + c)
                                  : (st + (size_t)row * Hdim + (c - Hdim));
    float4 v0 = *(const float4*)(src + lane * 4);
    float4 v1 = *(const float4*)(src + 256 + lane * 4);
    short4v o0, o1;
    o0[0] = f2bf(v0.x); o0[1] = f2bf(v0.y); o0[2] = f2bf(v0.z); o0[3] = f2bf(v0.w);
    o1[0] = f2bf(v1.x); o1[1] = f2bf(v1.y); o1[2] = f2bf(v1.z); o1[3] = f2bf(v1.w);
    short* d = A + base;
    *(short4v*)(d + lane * 4) = o0;
    *(short4v*)(d + 256 + lane * 4) = o1;
}

// ---------------------------------------------------------------------------
// Kernel 3: fused GEMM, 8-phase 256^2 schedule (T1+T2+T3+T4+T5).
// Schedule byte-identical to the proven R1/R3 kernel; ONLY change: h is
// stored as bf16 (halves the h round-trip: 64->32 MB write here, 64->32 MB
// read in ln_k).
// ---------------------------------------------------------------------------
__device__ __forceinline__ void rdA4(const short* base, const int i0,
                                     short8 (&aF)[4][2],
                                     const int cs0, const int cs1) {
#pragma unroll
    for (int i = 0; i < 4; ++i) {
        aF[i][0] = *(const short8*)(base + (i0 + i) * 16 * BK + cs0);
        aF[i][1] = *(const short8*)(base + (i0 + i) * 16 * BK + cs1);
    }
}
__device__ __forceinline__ void rdB2(const short* base, const int j0,
                                     short8 (&bF)[2][2],
                                     const int cs0, const int cs1) {
#pragma unroll
    for (int j = 0; j < 2; ++j) {
        bF[j][0] = *(const short8*)(base + (j0 + j) * 16 * BK + cs0);
        bF[j][1] = *(const short8*)(base + (j0 + j) * 16 * BK + cs1);
    }
}
__device__ __forceinline__ void mma16(floatx4 (&acc)[8][4], const int ia,
                                      const int jb, const short8 (&aF)[4][2],
                                      const short8 (&bF)[2][2]) {
#pragma unroll
    for (int i = 0; i < 4; ++i)
#pragma unroll
        for (int j = 0; j < 2; ++j) {
            acc[ia + i][jb + j] = __builtin_amdgcn_mfma_f32_16x16x32_bf16(
                aF[i][0], bF[j][0], acc[ia + i][jb + j], 0, 0, 0);
            acc[ia + i][jb + j] = __builtin_amdgcn_mfma_f32_16x16x32_bf16(
                aF[i][1], bF[j][1], acc[ia + i][jb + j], 0, 0, 0);
        }
}

#define STAGE(srcArr, h, dstBase, dstOff, koff) do {               \
    g2l16(srcArr[h][0] + (koff), (dstBase) + dstOff[h][0]);        \
    g2l16(srcArr[h][1] + (koff), (dstBase) + dstOff[h][1]); } while (0)

#define BAR()   __builtin_amdgcn_s_barrier()
#define LGKM0() asm volatile("s_waitcnt lgkmcnt(0)" ::: "memory")
#define VM6()   asm volatile("s_waitcnt vmcnt(6)" ::: "memory")
#define VM0()   asm volatile("s_waitcnt vmcnt(0)" ::: "memory")
#define PRIO1() __builtin_amdgcn_s_setprio(1)
#define PRIO0() __builtin_amdgcn_s_setprio(0)

__global__ __launch_bounds__(512, 2) void gemm_fused(
    const short* __restrict__ A,    // [8192][4096] bf16
    const short* __restrict__ Bt,   // [4096][4096] bf16 (cand|gate rows)
    const float* __restrict__ st,   // [8192][2048]
    const float* __restrict__ bc, const float* __restrict__ bg,
    const float* __restrict__ lstep,
    short* __restrict__ Hout)       // [8192][2048] bf16
{
    __shared__ __attribute__((aligned(16))) short lds[4][256 * BK];
    short* const sA0 = &lds[0][0];
    short* const sA1 = &lds[1][0];
    short* const sB0 = &lds[2][0];
    short* const sB1 = &lds[3][0];

    const int tid  = threadIdx.x;
    const int lane = tid & 63;
    const int w    = tid >> 6;
    const int wm = w >> 2;
    const int wn = w & 3;

    const int bid = blockIdx.x;
    const int swz = (bid & 7) * 64 + (bid >> 3);   // XCD-bijective (512%8==0)
    const int m0 = (swz >> 4) * BM;
    const int n0 = (swz & 15) * BNH;

    const int r8 = lane >> 3;
    const int c8 = ((lane & 7) ^ r8) * 8;
    const short* aSrc[2][2];
    const short* bSrc[2][2];
    int dstA[2][2], dstB[2][2];
#pragma unroll
    for (int hh = 0; hh < 2; ++hh)
#pragma unroll
        for (int q = 0; q < 2; ++q) {
            int f = w * 2 + q;
            int ra = f * 8 + hh * 64 + (f & 8) * 8;
            int rb = (f >> 2) * 64 + (f & 3) * 8 + hh * 32;
            aSrc[hh][q] = A + (size_t)(m0 + ra + r8) * Kdim + c8;
            int lr = rb + r8;
            int btrow = n0 + ((lr >> 6) << 5) + (lr & 31)
                        + ((lr & 32) ? Hdim : 0);
            bSrc[hh][q] = Bt + (size_t)btrow * Kdim + c8;
            dstA[hh][q] = ra * BK;
            dstB[hh][q] = rb * BK;
        }

    const int fr = lane & 15;
    const int j4 = lane >> 4;
    const int cs0 = ((j4 ^ (fr & 7)) * 8);
    const int cs1 = (((4 + j4) ^ (fr & 7)) * 8);
    const short* A0f = sA0 + (wm * 128 + fr) * BK;
    const short* A1f = sA1 + (wm * 128 + fr) * BK;
    const short* B0f = sB0 + (wn * 64 + fr) * BK;
    const short* B1f = sB1 + (wn * 64 + fr) * BK;

    floatx4 acc[8][4];
#pragma unroll
    for (int i = 0; i < 8; ++i)
#pragma unroll
        for (int j = 0; j < 4; ++j) {
            floatx4 z = {0.f, 0.f, 0.f, 0.f};
            acc[i][j] = z;
        }
    short8 aF[4][2], bLo[2][2], bHi[2][2];

    // prologue: t0 fully (8 loads), t1 minus A-h1 (6 loads)
    STAGE(aSrc, 0, sA0, dstA, 0);
    STAGE(aSrc, 1, sA0, dstA, 0);
    STAGE(bSrc, 0, sB0, dstB, 0);
    STAGE(bSrc, 1, sB0, dstB, 0);
    STAGE(aSrc, 0, sA1, dstA, BK);
    STAGE(bSrc, 0, sB1, dstB, BK);
    STAGE(bSrc, 1, sB1, dstB, BK);
    VM6();
    BAR();

    for (int it = 0; it < NITER; ++it) {
        const bool nl = (it < NITER - 1);
        const int k1  = (2 * it + 1) * BK;
        const int k02 = (2 * it + 2) * BK;
        const int k12 = (2 * it + 3) * BK;

        // P1
        rdA4(A0f, 0, aF, cs0, cs1);
        rdB2(B0f, 0, bLo, cs0, cs1);
        STAGE(aSrc, 1, sA1, dstA, k1);
        BAR(); LGKM0(); PRIO1();
        mma16(acc, 0, 0, aF, bLo);
        PRIO0(); BAR();
        // P2
        rdB2(B0f, 2, bHi, cs0, cs1);
        if (nl) { STAGE(aSrc, 0, sA0, dstA, k02); }
        BAR(); LGKM0(); PRIO1();
        mma16(acc, 0, 2, aF, bHi);
        PRIO0(); BAR();
        // P3
        rdA4(A0f, 4, aF, cs0, cs1);
        if (nl) { STAGE(bSrc, 0, sB0, dstB, k02); }
        BAR(); LGKM0(); PRIO1();
        mma16(acc, 4, 0, aF, bLo);
        PRIO0(); BAR();
        // P4
        if (nl) { STAGE(bSrc, 1, sB0, dstB, k02); VM6(); }
        else    { VM0(); }
        BAR(); PRIO1();
        mma16(acc, 4, 2, aF, bHi);
        PRIO0(); BAR();
        // P5
        rdA4(A1f, 0, aF, cs0, cs1);
        rdB2(B1f, 0, bLo, cs0, cs1);
        if (nl) { STAGE(aSrc, 1, sA0, dstA, k02); }
        BAR(); LGKM0(); PRIO1();
        mma16(acc, 0, 0, aF, bLo);
        PRIO0(); BAR();
        // P6
        rdB2(B1f, 2, bHi, cs0, cs1);
        if (nl) { STAGE(aSrc, 0, sA1, dstA, k12); }
        BAR(); LGKM0(); PRIO1();
        mma16(acc, 0, 2, aF, bHi);
        PRIO0(); BAR();
        // P7
        rdA4(A1f, 4, aF, cs0, cs1);
        if (nl) { STAGE(bSrc, 0, sB1, dstB, k12); }
        BAR(); LGKM0(); PRIO1();
        mma16(acc, 4, 0, aF, bLo);
        PRIO0(); BAR();
        // P8
        if (nl) { STAGE(bSrc, 1, sB1, dstB, k12); VM6(); }
        BAR(); PRIO1();
        mma16(acc, 4, 2, aF, bHi);
        PRIO0(); BAR();
    }

    // epilogue: gating, intra-lane cand(j) x gate(j+2); h stored bf16
    const int cn = lane & 15;
    const int cr = j4 * 4;
    float bcv[2], bgv[2], alv[2];
#pragma unroll
    for (int j = 0; j < 2; ++j) {
        int col = n0 + wn * 32 + j * 16 + cn;
        bcv[j] = bc[col];
        bgv[j] = bg[col];
        alv[j] = __expf(-__expf(-lstep[col]));
    }
#pragma unroll
    for (int i = 0; i < 8; ++i) {
        int rowb = m0 + wm * 128 + i * 16 + cr;
#pragma unroll
        for (int r = 0; r < 4; ++r) {
            int row = rowb + r;
            const float* sp = st + (size_t)row * Hdim;
            short* hp = Hout + (size_t)row * Hdim;
#pragma unroll
            for (int j = 0; j < 2; ++j) {
                int col = n0 + wn * 32 + j * 16 + cn;
                float cand = fast_tanh(acc[i][j][r] + bcv[j]);
                float gate = fast_sigmoid(acc[i][j + 2][r] + bgv[j]);
                float al = alv[j];
                hp[col] = f2bf(al * sp[col] + (1.f - al) * gate * cand);
            }
        }
    }
}

// ---------------------------------------------------------------------------
// Kernel 4 v3: LayerNorm, one WAVE per row, bf16 h input (short8 16B/lane,
// 1KB/wave-instr contiguous), fp32 output.
// ---------------------------------------------------------------------------
__global__ __launch_bounds__(256) void ln_k(
    const short* __restrict__ h, const float* __restrict__ gam,
    const float* __restrict__ bet, float* __restrict__ out)
{
    const int lane = threadIdx.x & 63;
    const int b = blockIdx.x * 4 + (threadIdx.x >> 6);
    const short* hp = h + (size_t)b * Hdim;

    float hv[32];
    float sum = 0.f, ss = 0.f;
#pragma unroll
    for (int q = 0; q < 4; ++q) {
        short8 v = *(const short8*)(hp + q * 512 + lane * 8);
#pragma unroll
        for (int e = 0; e < 8; ++e) {
            float f = bf2f(v[e]);
            hv[q * 8 + e] = f;
            sum += f; ss += f * f;
        }
    }
#pragma unroll
    for (int off = 1; off < 64; off <<= 1) {
        sum += __shfl_xor(sum, off);
        ss  += __shfl_xor(ss, off);
    }
    const float inv = 1.f / (float)Hdim;
    float mu = sum * inv;
    float var = ss * inv - mu * mu;
    float rs = rsqrtf(var + 1e-5f);
    float* op = out + (size_t)b * Hdim;
#pragma unroll
    for (int q = 0; q < 4; ++q) {
#pragma unroll
        for (int hq = 0; hq < 2; ++hq) {
            const int o8 = q * 512 + lane * 8 + hq * 4;
            float4 g  = *(const float4*)(gam + o8);
            float4 be = *(const float4*)(bet + o8);
            float4 o;
            o.x = (hv[q * 8 + hq * 4 + 0] - mu) * rs * g.x + be.x;
            o.y = (hv[q * 8 + hq * 4 + 1] - mu) * rs * g.y + be.y;
            o.z = (hv[q * 8 + hq * 4 + 2] - mu) * rs * g.z + be.z;
            o.w = (hv[q * 8 + hq * 4 + 3] - mu) * rs * g.w + be.w;
            *(float4*)(op + o8) = o;
        }
    }
}

// ---------------------------------------------------------------------------
extern "C" void kernel_launch(void* const* d_in, const int* in_sizes, int n_in,
                              void* d_out, int out_size, void* d_ws, size_t ws_size,
                              hipStream_t stream)
{
    const float* x_t   = (const float*)d_in[0];
    const float* state = (const float*)d_in[1];
    const float* Wc    = (const float*)d_in[2];
    const float* Uc    = (const float*)d_in[3];
    const float* bc    = (const float*)d_in[4];
    const float* Wg    = (const float*)d_in[5];
    const float* Ug    = (const float*)d_in[6];
    const float* bg    = (const float*)d_in[7];
    const float* lstep = (const float*)d_in[8];
    const float* gam   = (const float*)d_in[9];
    const float* bet   = (const float*)d_in[10];
    float* out = (float*)d_out;

    // workspace: Wt (32MB) | Acat (64MB) | h (32MB bf16) = 128MB
    char* ws = (char*)d_ws;
    short* Wt   = (short*)ws;
    short* Acat = (short*)(ws + (size_t)32 * 1024 * 1024);
    short* h    = (short*)(ws + (size_t)96 * 1024 * 1024);

    build_wt<<<dim3(Nall / 64, Kdim / 256), 256, 0, stream>>>(Wc, Uc, Wg, Ug, Wt);
    build_acat<<<(Bsz * (Kdim / 8)) / 256, 256, 0, stream>>>(x_t, state, Acat);
    gemm_fused<<<dim3((Bsz / BM) * (Hdim / BNH)), 512, 0, stream>>>(
        Acat, Wt, state, bc, bg, lstep, h);
    ln_k<<<Bsz / 4, 256, 0, stream>>>(h, gam, bet, out);
}